// Round 20
// baseline (39.895 us; speedup 1.0000x reference)
//
#include <hip/hip_runtime.h>
#include <math.h>

#define BB 4
#define ND 256
#define NE 512
#define CC 256

#define K2E 2.8853900817779268f   // 2 * log2(e): exp2(K2E*x) = e^{2x}
#define LOG2E 1.4426950408889634f
#define LN2 0.6931471805599453f

typedef unsigned int u32;
typedef unsigned short u16;
typedef __attribute__((ext_vector_type(8))) short bf16x8;   // 8 bf16 (4 VGPR)
typedef __attribute__((ext_vector_type(4))) float f32x4;
typedef __attribute__((ext_vector_type(4))) u32   u32x4;

__device__ __forceinline__ float bflo(u32 u) { return __builtin_bit_cast(float, u << 16); }
__device__ __forceinline__ float bfhi(u32 u) { return __builtin_bit_cast(float, u & 0xffff0000u); }

// pack 2 f32 -> 1 u32 of 2 bf16 (lo in [15:0], hi in [31:16])
__device__ __forceinline__ u32 cvt_pk(float lo, float hi) {
    u32 r;
    asm("v_cvt_pk_bf16_f32 %0, %1, %2" : "=v"(r) : "v"(lo), "v"(hi));
    return r;
}

__device__ __forceinline__ bf16x8 mk_frag(float4 f0, float4 f1) {
    u32x4 q;
    q.x = cvt_pk(f0.x, f0.y);
    q.y = cvt_pk(f0.z, f0.w);
    q.z = cvt_pk(f1.x, f1.y);
    q.w = cvt_pk(f1.z, f1.w);
    return __builtin_bit_cast(bf16x8, q);
}

// ---------------------------------------------------------------------------
// MFMA projection — R17 VERBATIM (11.9us measured R18; untouched this round).
// ---------------------------------------------------------------------------
__global__ __launch_bounds__(256) void proj_kernel(
    const float* __restrict__ xdec, const float* __restrict__ xenc,
    const float* __restrict__ w1,   const float* __restrict__ w2,
    uint4* __restrict__ Et4, float* __restrict__ Dexp)
{
    __shared__ float Ct[64][17];   // C staging for enc pack-transpose

    const int row0 = blockIdx.x * 64;     // M base (0..3071)
    const int col0 = blockIdx.y * 16;     // N base (0..240)
    const bool is_enc = (row0 < BB * NE);

    const float* X = is_enc ? xenc : xdec;
    const float* W = is_enc ? w1   : w2;
    const int xrow0 = is_enc ? row0 : (row0 - BB * NE);

    const int tid = threadIdx.x;
    const int wv  = tid >> 6;        // wave 0..3
    const int l   = tid & 63;
    const int lm  = l & 15;          // fragment row (A) / col (B)
    const int kg  = l >> 4;          // k-group 0..3

    const float* Arow = X + (size_t)(xrow0 + wv * 16 + lm) * CC + kg * 8;
    const float* Brow = W + (size_t)(col0 + lm) * CC + kg * 8;

    f32x4 acc = {0.f, 0.f, 0.f, 0.f};
#pragma unroll
    for (int ks = 0; ks < 8; ++ks) {
        const float* ap = Arow + ks * 32;
        const float* bp = Brow + ks * 32;
        bf16x8 af = mk_frag(*(const float4*)ap, *(const float4*)(ap + 4));
        bf16x8 bf = mk_frag(*(const float4*)bp, *(const float4*)(bp + 4));
        acc = __builtin_amdgcn_mfma_f32_16x16x32_bf16(af, bf, acc, 0, 0, 0);
    }

    float ex[4];
#pragma unroll
    for (int i = 0; i < 4; ++i)
        ex[i] = __builtin_amdgcn_exp2f(
            K2E * fminf(fmaxf(acc[i], -9.f), 9.f));

    if (is_enc) {
#pragma unroll
        for (int i = 0; i < 4; ++i)
            Ct[wv * 16 + kg * 4 + i][lm] = ex[i];
        __syncthreads();
        if (tid < 128) {
            const int e   = tid & 63;
            const int cqL = tid >> 6;        // 0..1
            const int b   = row0 >> 9;
            const int e0  = row0 & 511;
            const float* cr = &Ct[e][cqL * 8];
            u32x4 q;
            q.x = cvt_pk(cr[0], cr[1]);
            q.y = cvt_pk(cr[2], cr[3]);
            q.z = cvt_pk(cr[4], cr[5]);
            q.w = cvt_pk(cr[6], cr[7]);
            Et4[((size_t)b * 32 + (col0 >> 3) + cqL) * 512 + e0 + e] =
                __builtin_bit_cast(uint4, q);
        }
    } else {
        const int n = xrow0 + wv * 16 + kg * 4;
#pragma unroll
        for (int i = 0; i < 4; ++i)
            Dexp[(size_t)(n + i) * CC + col0 + lm] = ex[i];
    }
}

// ---------------------------------------------------------------------------
// Fused tanh-dot with LDS-SHARED Et staging.
// Block = (b, 16 decoder rows, 64-e tile): 512 blocks x 512 thr.
// Phase A: stage Et4[b][all 32 cq][64 e] (32 KB) into LDS cooperatively.
// Phase B: thread (e = tid&63, rowgroup rg = tid>>6) does 2 rows x 256 c,
//          E from LDS. Et global traffic: 128 MB -> 16 MB (the R13/R6-R7
//          cold-L3 cost). Writes raw prod; lsm_kernel finishes.
//   p'[n,e] = -2 * sum_c v_c / (1 + E*D)    (sum(v) shift cancels)
//   v0/d0 + v1/d1 = (v0*d1 + v1*d0) / (d0*d1),  d = fma(E, D, 1)
// ---------------------------------------------------------------------------
__global__ __launch_bounds__(512) void attn_kernel(
    const uint4* __restrict__ Et4, const float* __restrict__ Dexp,
    const float* __restrict__ v, float* __restrict__ prod)
{
    __shared__ uint4 Es[32 * 64];   // [cq][e_local] = 32 KB

    const int blk = blockIdx.x;          // 0..511
    const int b   = blk >> 7;
    const int rem = blk & 127;           // nt*8 + eq
    const int nt  = rem >> 3;            // 0..15 -> n0 = nt*16
    const int eq  = rem & 7;             // 0..7  -> e0 = eq*64
    const int tid = threadIdx.x;
    const int e   = tid & 63;            // e_local
    const int rg  = tid >> 6;            // 0..7 -> rows n0 + rg*2, +1

    // Phase A: cooperative stage (coalesced: 64 consecutive e per cq row)
    for (int i = tid; i < 32 * 64; i += 512) {
        const int cq = i >> 6, el = i & 63;
        Es[i] = Et4[((size_t)b * 32 + cq) * 512 + eq * 64 + el];
    }
    __syncthreads();

    const int n0 = nt * 16;
    const float* __restrict__ D0 = Dexp + (size_t)(b * ND + n0 + rg * 2) * CC;
    const float* __restrict__ D1 = D0 + CC;

    float a0 = 0.f, a1 = 0.f;

#define PAIR(ACC, E0, E1, V0, V1, Dx0, Dx1) do {                             \
        const float _d0 = fmaf((E0), (Dx0), 1.0f);                           \
        const float _d1 = fmaf((E1), (Dx1), 1.0f);                           \
        const float _num = fmaf((V1), _d0, (V0) * _d1);                      \
        ACC = fmaf(_num, __builtin_amdgcn_rcpf(_d0 * _d1), ACC);             \
    } while (0)

#pragma unroll 4
    for (int cq = 0; cq < 32; ++cq) {
        const uint4 E4 = Es[cq * 64 + e];
        const int c8 = cq * 8;
        const float4 vA  = *(const float4*)&v [c8];
        const float4 vB  = *(const float4*)&v [c8 + 4];
        const float4 dA0 = *(const float4*)&D0[c8];
        const float4 dB0 = *(const float4*)&D0[c8 + 4];
        const float4 dA1 = *(const float4*)&D1[c8];
        const float4 dB1 = *(const float4*)&D1[c8 + 4];
        PAIR(a0, bflo(E4.x), bfhi(E4.x), vA.x, vA.y, dA0.x, dA0.y);
        PAIR(a1, bflo(E4.x), bfhi(E4.x), vA.x, vA.y, dA1.x, dA1.y);
        PAIR(a0, bflo(E4.y), bfhi(E4.y), vA.z, vA.w, dA0.z, dA0.w);
        PAIR(a1, bflo(E4.y), bfhi(E4.y), vA.z, vA.w, dA1.z, dA1.w);
        PAIR(a0, bflo(E4.z), bfhi(E4.z), vB.x, vB.y, dB0.x, dB0.y);
        PAIR(a1, bflo(E4.z), bfhi(E4.z), vB.x, vB.y, dB1.x, dB1.y);
        PAIR(a0, bflo(E4.w), bfhi(E4.w), vB.z, vB.w, dB0.z, dB0.w);
        PAIR(a1, bflo(E4.w), bfhi(E4.w), vB.z, vB.w, dB1.z, dB1.w);
    }
#undef PAIR

    float* pr = prod + (size_t)(b * ND + n0 + rg * 2) * NE + eq * 64 + e;
    pr[0]  = -2.0f * a0;
    pr[NE] = -2.0f * a1;
}

// ---------------------------------------------------------------------------
// log_softmax over e (512) per (b,n) row. One wave per row, 4 rows/block.
// ---------------------------------------------------------------------------
__global__ __launch_bounds__(256) void lsm_kernel(
    const float* __restrict__ prod, float* __restrict__ out)
{
    const int row  = blockIdx.x * 4 + (threadIdx.x >> 6);
    const int lane = threadIdx.x & 63;
    const float* p = prod + (size_t)row * NE;

    float x[8];
#pragma unroll
    for (int i = 0; i < 8; ++i) x[i] = p[lane + 64 * i];
    float m = x[0];
#pragma unroll
    for (int i = 1; i < 8; ++i) m = fmaxf(m, x[i]);
#pragma unroll
    for (int off = 1; off < 64; off <<= 1) m = fmaxf(m, __shfl_xor(m, off));
    float s = 0.f;
#pragma unroll
    for (int i = 0; i < 8; ++i) s += __builtin_amdgcn_exp2f((x[i] - m) * LOG2E);
#pragma unroll
    for (int off = 1; off < 64; off <<= 1) s += __shfl_xor(s, off);
    const float lse = m + __builtin_amdgcn_logf(s) * LN2;

    float* o = out + (size_t)row * NE;
#pragma unroll
    for (int i = 0; i < 8; ++i) o[lane + 64 * i] = x[i] - lse;
}

// ---------------------------------------------------------------------------
extern "C" void kernel_launch(void* const* d_in, const int* in_sizes, int n_in,
                              void* d_out, int out_size, void* d_ws, size_t ws_size,
                              hipStream_t stream) {
    const float* xdec = (const float*)d_in[0];   // (4,256,256)
    const float* xenc = (const float*)d_in[1];   // (4,512,256)
    const float* w1   = (const float*)d_in[2];   // (256,256)
    const float* w2   = (const float*)d_in[3];   // (256,256)
    const float* v    = (const float*)d_in[4];   // (1,256)
    float* out = (float*)d_out;                  // (4,256,512)

    char* ws = (char*)d_ws;
    uint4* Et4  = (uint4*)ws;                    // [4][32][512] uint4 = 1 MB
    float* Dexp = (float*)(ws + (1u << 20));     // [1024][256] f32 = 1 MB
    float* prod = (float*)(ws + (2u << 20));     // [1024][512] f32 = 2 MB

    dim3 gproj(48, 16);
    proj_kernel<<<gproj, 256, 0, stream>>>(xdec, xenc, w1, w2, Et4, Dexp);
    attn_kernel<<<512, 512, 0, stream>>>(Et4, Dexp, v, prod);
    lsm_kernel<<<256, 256, 0, stream>>>(prod, out);
}